// Round 6
// baseline (155.808 us; speedup 1.0000x reference)
//
#include <hip/hip_runtime.h>
#include <hip/hip_bf16.h>
#include <stdint.h>

// Problem constants
#define T_TOK 2048
#define H_DIM 1024
#define I_DIM 768
#define E_NUM 16
#define K_TOP 4
#define NSLOT 8192          // (token,k) slots
#define PSLOT 12288         // slot capacity padded to 256/expert
#define NT256 48            // 256-row M tiles
#define NT128 96            // 128-row M tiles
#define RTOT_GU 24576       // 16*1536 rows of gate_up

typedef short  s16x8 __attribute__((ext_vector_type(8)));
typedef float  f32x4 __attribute__((ext_vector_type(4)));
typedef unsigned short u16x8 __attribute__((ext_vector_type(8)));
typedef unsigned short u16x4 __attribute__((ext_vector_type(4)));

#define MEMFENCE asm volatile("" ::: "memory")

__device__ __forceinline__ void gload16(const void* g, void* l) {
  __builtin_amdgcn_global_load_lds(
      (const __attribute__((address_space(1))) uint32_t*)g,
      (__attribute__((address_space(3))) uint32_t*)l, 16, 0, 0);
}

__device__ __forceinline__ unsigned short f2bf(float f) {
  __hip_bfloat16 h = __float2bfloat16(f);
  return *reinterpret_cast<unsigned short*>(&h);
}

// ---------------- fp32 -> bf16 conversion (X only) -------------------------
__global__ __launch_bounds__(256) void cvt_bf16_kernel(
    const float* __restrict__ in, unsigned short* __restrict__ out, int n8) {
  int i = blockIdx.x * 256 + threadIdx.x;
  if (i >= n8) return;
  const float4* p = (const float4*)in;
  float4 a = p[2 * (size_t)i];
  float4 b = p[2 * (size_t)i + 1];
  u16x8 o;
  o[0] = f2bf(a.x); o[1] = f2bf(a.y); o[2] = f2bf(a.z); o[3] = f2bf(a.w);
  o[4] = f2bf(b.x); o[5] = f2bf(b.y); o[6] = f2bf(b.z); o[7] = f2bf(b.w);
  *(u16x8*)(out + (size_t)i * 8) = o;
}

// ---------------- Wgu fp32 row-major -> bf16 K-major [kt][row][64] ---------
// Block: 16 rows, full K. Linear coalesced read, LDS stage, contiguous write.
__global__ __launch_bounds__(256) void wtrans_kernel(
    const float* __restrict__ in, unsigned short* __restrict__ out,
    int K, int RTOT) {
  __shared__ unsigned short tile[16 * 1024];
  int r0 = blockIdx.x * 16;
  int t = threadIdx.x;
  int nf4 = 16 * K / 4;
  const f32x4* src = (const f32x4*)(in + (size_t)r0 * K);
  for (int i = t; i < nf4; i += 256) {
    f32x4 v = src[i];
    u16x4 o;
    o[0] = f2bf(v[0]); o[1] = f2bf(v[1]); o[2] = f2bf(v[2]); o[3] = f2bf(v[3]);
    *(u16x4*)(tile + (size_t)i * 4) = o;
  }
  __syncthreads();
  int nkt = K / 64;
  int row = t >> 4, k4 = (t & 15) * 4;
  for (int kt = 0; kt < nkt; ++kt) {
    u16x4 v = *(const u16x4*)(tile + row * K + kt * 64 + k4);
    *(u16x4*)(out + ((size_t)kt * RTOT + r0 + row) * 64 + k4) = v;
  }
}

// ---------------- deterministic routing: stable counting sort ----------------
// Experts padded to 256-multiples; padding slots: token=0, weight=0.
__global__ __launch_bounds__(256) void route_kernel(
    const int* __restrict__ idx, const float* __restrict__ wts,
    int* __restrict__ slot_tok, float* __restrict__ slot_w,
    int* __restrict__ slot_of, int* __restrict__ tile_expert,
    int* __restrict__ tile_expert128) {
  __shared__ int cnt[256][16];
  __shared__ int tot[16];
  __shared__ int pb[17];
  int tid = threadIdx.x;

  for (int e = 0; e < 16; ++e) cnt[tid][e] = 0;
  const int s0 = tid * 32;
  for (int i = 0; i < 32; ++i) {
    int e = idx[s0 + i] & 15;
    cnt[tid][e]++;
  }
  __syncthreads();
  if (tid < 16) {
    int run = 0;
    for (int c = 0; c < 256; ++c) { int v = cnt[c][tid]; cnt[c][tid] = run; run += v; }
    tot[tid] = run;
  }
  __syncthreads();
  if (tid == 0) {
    int acc = 0;
    for (int e = 0; e < 16; ++e) { pb[e] = acc; acc += (tot[e] + 255) & ~255; }
    pb[16] = acc;
  }
  __syncthreads();
  for (int p = tid; p < PSLOT; p += 256) { slot_tok[p] = 0; slot_w[p] = 0.0f; }
  if (tid < NT256) {
    int ef = -1;
    for (int e = 0; e < 16; ++e)
      if (tid * 256 >= pb[e] && tid * 256 < pb[e + 1]) ef = e;
    tile_expert[tid] = ef;
  }
  if (tid >= 64 && tid < 64 + NT128) {
    int m = (tid - 64) * 128;
    int ef = -1;
    for (int e = 0; e < 16; ++e)
      if (m >= pb[e] && m < pb[e + 1]) ef = e;
    tile_expert128[tid - 64] = ef;
  }
  __syncthreads();
  for (int i = 0; i < 32; ++i) {
    int s = s0 + i;
    int e = idx[s] & 15;
    int pos = pb[e] + cnt[tid][e]++;
    slot_tok[pos] = s >> 2;
    slot_w[pos]   = wts[s];
    slot_of[s]    = pos;
  }
}

// ---------------- GEMM1: 256M x (128g|128u)N, BK=64, 8 waves, 2ph-1barrier --
// A: gathered slot rows of Xbf; B: K-major bf16 WguK. All staging via
// global_load_lds with source-pre-swizzle (slot ^= row&7); reads swizzled.
__global__ __launch_bounds__(512) void gemm1_kernel(
    const unsigned short* __restrict__ Xbf,       // [2048][1024] bf16
    const unsigned short* __restrict__ WguK,      // [16][24576][64] K-major bf16
    const int* __restrict__ slot_tok,
    const int* __restrict__ tile_expert,
    unsigned short* __restrict__ hbuf) {          // [PSLOT][768] bf16
  __shared__ char lds[131072];   // 2 bufs x (A 32KB + B 32KB)

  // XCD-chunked remap: 288 blocks, 36/XCD (288%8==0)
  int bid  = blockIdx.y * 6 + blockIdx.x;
  int sbid = (bid & 7) * 36 + (bid >> 3);
  int by = sbid / 6, bx = sbid % 6;
  int e = tile_expert[by];
  if (e < 0) return;
  int m0 = by * 256;
  int t = threadIdx.x;
  int lane = t & 63, w = t >> 6;
  int wr = w >> 2, wc = w & 3;        // 2M x 4N waves
  int l15 = lane & 15, lhi = lane >> 4;

  // ---- staging source addresses (pre-swizzled column) ----
  int rr = t >> 3;                    // 0..63 row within one gload call
  int lslot16 = ((t & 7) ^ (rr & 7)) * 16;
  const char* aS[4];
#pragma unroll
  for (int a = 0; a < 4; ++a) {
    int tok = slot_tok[m0 + a * 64 + rr];
    aS[a] = (const char*)Xbf + (size_t)tok * 2048 + lslot16;
  }
  const char* bS[4];
#pragma unroll
  for (int c = 0; c < 4; ++c) {
    int rg = e * 1536 + ((c < 2) ? 0 : 768) + bx * 128 + (c & 1) * 64 + rr;
    bS[c] = (const char*)WguK + (size_t)rg * 128 + lslot16;
  }

  f32x4 accg[8][2] = {};
  f32x4 accu[8][2] = {};

#define G1_STAGE(bi, kt) do {                                 \
    char* dst = lds + (bi) * 65536 + t * 16;                  \
    size_t ao = (size_t)(kt) * 128;                           \
    size_t bo = (size_t)(kt) * ((size_t)RTOT_GU * 128);       \
    MEMFENCE;                                                 \
    gload16(aS[0] + ao, dst);                                 \
    gload16(aS[1] + ao, dst + 8192);                          \
    gload16(aS[2] + ao, dst + 16384);                         \
    gload16(aS[3] + ao, dst + 24576);                         \
    gload16(bS[0] + bo, dst + 32768);                         \
    gload16(bS[1] + bo, dst + 40960);                         \
    gload16(bS[2] + bo, dst + 49152);                         \
    gload16(bS[3] + bo, dst + 57344);                         \
    MEMFENCE;                                                 \
  } while (0)

#define G1_COMPUTE(bi) do {                                                        \
    const short* La = (const short*)(lds + (bi) * 65536);                          \
    const short* Lb = La + 16384;                                                  \
    _Pragma("unroll")                                                              \
    for (int ks = 0; ks < 2; ++ks) {                                               \
      int p8 = (((ks) * 4 + lhi) ^ (l15 & 7)) * 8;                                 \
      s16x8 af[8], bg[2], bu[2];                                                   \
      _Pragma("unroll")                                                            \
      for (int mi = 0; mi < 8; ++mi)                                               \
        af[mi] = *(const s16x8*)(La + (wr * 128 + mi * 16 + l15) * 64 + p8);       \
      _Pragma("unroll")                                                            \
      for (int ni = 0; ni < 2; ++ni) {                                             \
        bg[ni] = *(const s16x8*)(Lb + (wc * 32 + ni * 16 + l15) * 64 + p8);        \
        bu[ni] = *(const s16x8*)(Lb + (128 + wc * 32 + ni * 16 + l15) * 64 + p8);  \
      }                                                                            \
      __builtin_amdgcn_s_setprio(1);                                               \
      _Pragma("unroll")                                                            \
      for (int mi = 0; mi < 8; ++mi)                                               \
        _Pragma("unroll")                                                          \
        for (int ni = 0; ni < 2; ++ni) {                                           \
          accg[mi][ni] = __builtin_amdgcn_mfma_f32_16x16x32_bf16(af[mi], bg[ni], accg[mi][ni], 0, 0, 0); \
          accu[mi][ni] = __builtin_amdgcn_mfma_f32_16x16x32_bf16(af[mi], bu[ni], accu[mi][ni], 0, 0, 0); \
        }                                                                          \
      __builtin_amdgcn_s_setprio(0);                                               \
    }                                                                              \
  } while (0)

  // prologue
  G1_STAGE(0, 0);
  asm volatile("s_waitcnt vmcnt(0)" ::: "memory");
  __builtin_amdgcn_s_barrier();
  MEMFENCE;

  int cur = 0;
  for (int kt = 0; kt < 16; ++kt) {
    if (kt + 1 < 16) G1_STAGE(cur ^ 1, kt + 1);
    G1_COMPUTE(cur);
    asm volatile("s_waitcnt vmcnt(0)" ::: "memory");
    __builtin_amdgcn_s_barrier();
    MEMFENCE;
    cur ^= 1;
  }
#undef G1_STAGE
#undef G1_COMPUTE

  // epilogue: h = silu(g)*u ; C layout col=lane&15, row=(lane>>4)*4+q
#pragma unroll
  for (int mi = 0; mi < 8; ++mi) {
#pragma unroll
    for (int ni = 0; ni < 2; ++ni) {
      int col = bx * 128 + wc * 32 + ni * 16 + l15;
#pragma unroll
      for (int q = 0; q < 4; ++q) {
        int m = m0 + wr * 128 + mi * 16 + lhi * 4 + q;
        float g = accg[mi][ni][q];
        float u = accu[mi][ni][q];
        float s = g / (1.0f + __expf(-g));
        hbuf[(size_t)m * I_DIM + col] = f2bf(s * u);
      }
    }
  }
}

// ---------------- GEMM2 (R5 structure, fused fp32 Wd): y = (h@Wd^T)*w -------
__global__ __launch_bounds__(256) void gemm2_kernel(
    const unsigned short* __restrict__ hbuf,
    const float* __restrict__ Wd,                 // [16][1024][768] fp32
    const int* __restrict__ slot_tok,
    const float* __restrict__ slot_w,
    const int* __restrict__ tile_expert128,
    float* __restrict__ y) {                      // [PSLOT][1024] fp32
  // XCD-chunked remap: 768 blocks, 96/XCD
  int bid  = blockIdx.y * 8 + blockIdx.x;
  int sbid = (bid & 7) * 96 + (bid >> 3);
  int by   = sbid >> 3;
  int bx   = sbid & 7;
  int e = tile_expert128[by];
  if (e < 0) return;
  int m0 = by * 128;
  int tid = threadIdx.x;
  int lane = tid & 63, w = tid >> 6;
  int wr = w >> 1, wc = w & 1;

  __shared__ short lds[2 * 8192];
  char* buf0 = (char*)lds;
  char* buf1 = buf0 + 16384;

  int srow = tid >> 2;
  int swzc = ((tid & 3) ^ ((tid >> 3) & 3)) * 16;
  const char* gA0 = (const char*)(hbuf + (size_t)(m0 + srow) * I_DIM) + swzc;
  const char* gA1 = (const char*)(hbuf + (size_t)(m0 + 64 + srow) * I_DIM) + swzc;

  int brow = tid >> 1;
  int half = tid & 1;
  const float* gB = Wd + ((size_t)e * 1024 + bx * 128 + brow) * I_DIM + half * 16;

  int pswz = ((lane >> 4) ^ (((lane & 15) >> 1) & 3)) * 8;

  f32x4 acc[4][4] = {};
  f32x4 s0_0, s0_1, s0_2, s0_3, s1_0, s1_1, s1_2, s1_3;
  f32x4 s2_0, s2_1, s2_2, s2_3, s3_0, s3_1, s3_2, s3_3;

  // fp32x16 -> two swizzled bf16x8 LDS writes
#define WR_BROW(bregion, r, h_, f0, f1, f2, f3) do {          \
    u16x8 c0, c1;                                             \
    c0[0]=f2bf(f0[0]); c0[1]=f2bf(f0[1]); c0[2]=f2bf(f0[2]); c0[3]=f2bf(f0[3]); \
    c0[4]=f2bf(f1[0]); c0[5]=f2bf(f1[1]); c0[6]=f2bf(f1[2]); c0[7]=f2bf(f1[3]); \
    c1[0]=f2bf(f2[0]); c1[1]=f2bf(f2[1]); c1[2]=f2bf(f2[2]); c1[3]=f2bf(f2[3]); \
    c1[4]=f2bf(f3[0]); c1[5]=f2bf(f3[1]); c1[6]=f2bf(f3[2]); c1[7]=f2bf(f3[3]); \
    int xr = ((r) >> 1) & 3;                                  \
    char* wb = (bregion) + (r) * 64;                          \
    *(u16x8*)(wb + (((2*(h_) + 0) ^ xr) * 16)) = c0;          \
    *(u16x8*)(wb + (((2*(h_) + 1) ^ xr) * 16)) = c1;          \
  } while (0)

#define NT2 24
#define A_GLOAD2(kt, bufp) do {                               \
    int kk_ = (kt) < NT2 ? (kt) : NT2 - 1;                    \
    int ko_ = kk_ * 64;                                       \
    gload16(gA0 + ko_, (bufp) + tid * 16);                    \
    gload16(gA1 + ko_, (bufp) + 4096 + tid * 16);             \
  } while (0)
#define B_LOAD2(v0, v1, v2, v3, kt) do {                      \
    int kk_ = (kt) < NT2 ? (kt) : NT2 - 1;                    \
    const f32x4* p_ = (const f32x4*)(gB + (size_t)kk_ * 32);  \
    v0 = p_[0]; v1 = p_[1]; v2 = p_[2]; v3 = p_[3];           \
  } while (0)

#define G2_COMPUTE(bufp) do {                                                          \
    const short* La = (const short*)(bufp);                                            \
    s16x8 af[4], bf[4];                                                                \
    _Pragma("unroll")                                                                  \
    for (int mi = 0; mi < 4; ++mi)                                                     \
      af[mi] = *(const s16x8*)(La + (wr * 64 + mi * 16 + (lane & 15)) * 32 + pswz);    \
    _Pragma("unroll")                                                                  \
    for (int ni = 0; ni < 4; ++ni)                                                     \
      bf[ni] = *(const s16x8*)(La + 4096 + (wc * 64 + ni * 16 + (lane & 15)) * 32 + pswz); \
    _Pragma("unroll")                                                                  \
    for (int mi = 0; mi < 4; ++mi)                                                     \
      _Pragma("unroll")                                                                \
      for (int ni = 0; ni < 4; ++ni)                                                   \
        acc[mi][ni] = __builtin_amdgcn_mfma_f32_16x16x32_bf16(af[mi], bf[ni], acc[mi][ni], 0, 0, 0); \
  } while (0)

#define ITER2(kt, wv0, wv1, wv2, wv3, lv0, lv1, lv2, lv3) do {  \
    char* cbuf_ = ((kt) & 1) ? buf1 : buf0;                     \
    char* nbuf_ = ((kt) & 1) ? buf0 : buf1;                     \
    MEMFENCE;                                                   \
    A_GLOAD2((kt) + 1, nbuf_);                                  \
    MEMFENCE;                                                   \
    B_LOAD2(lv0, lv1, lv2, lv3, (kt) + 3);                      \
    asm volatile("s_waitcnt vmcnt(10)" ::: "memory");           \
    WR_BROW(nbuf_ + 8192, brow, half, wv0, wv1, wv2, wv3);      \
    asm volatile("s_waitcnt lgkmcnt(0)" ::: "memory");          \
    __builtin_amdgcn_s_barrier();                               \
    MEMFENCE;                                                   \
    G2_COMPUTE(cbuf_);                                          \
    MEMFENCE;                                                   \
    __builtin_amdgcn_s_barrier();                               \
  } while (0)

  A_GLOAD2(0, buf0);
  MEMFENCE;
  B_LOAD2(s0_0, s0_1, s0_2, s0_3, 0);
  MEMFENCE;
  B_LOAD2(s1_0, s1_1, s1_2, s1_3, 1);
  MEMFENCE;
  B_LOAD2(s2_0, s2_1, s2_2, s2_3, 2);
  asm volatile("s_waitcnt vmcnt(8)" ::: "memory");
  WR_BROW(buf0 + 8192, brow, half, s0_0, s0_1, s0_2, s0_3);

  for (int kt = 0; kt < NT2; kt += 4) {
    ITER2(kt + 0, s1_0, s1_1, s1_2, s1_3, s3_0, s3_1, s3_2, s3_3);
    ITER2(kt + 1, s2_0, s2_1, s2_2, s2_3, s0_0, s0_1, s0_2, s0_3);
    ITER2(kt + 2, s3_0, s3_1, s3_2, s3_3, s1_0, s1_1, s1_2, s1_3);
    ITER2(kt + 3, s0_0, s0_1, s0_2, s0_3, s2_0, s2_1, s2_2, s2_3);
  }
#undef ITER2
#undef G2_COMPUTE
#undef B_LOAD2
#undef A_GLOAD2
#undef WR_BROW

#pragma unroll
  for (int mi = 0; mi < 4; ++mi) {
#pragma unroll
    for (int q = 0; q < 4; ++q) {
      int m = m0 + wr * 64 + mi * 16 + (lane >> 4) * 4 + q;
      float wgt = slot_w[m];
      float* orow = y + (size_t)m * H_DIM + bx * 128 + wc * 64 + (lane & 15);
#pragma unroll
      for (int ni = 0; ni < 4; ++ni)
        orow[ni * 16] = acc[mi][ni][q] * wgt;
    }
  }
}

// ---------------- combine: out[t] = sum_k y[slot_of[t,k]] -------------------
__global__ __launch_bounds__(256) void combine_kernel(
    const float* __restrict__ y, const int* __restrict__ slot_of,
    float* __restrict__ out) {
  int t = blockIdx.x;
  int c = threadIdx.x * 4;
  int s0 = slot_of[t * 4 + 0], s1 = slot_of[t * 4 + 1];
  int s2 = slot_of[t * 4 + 2], s3 = slot_of[t * 4 + 3];
  f32x4 v0 = *(const f32x4*)(y + (size_t)s0 * H_DIM + c);
  f32x4 v1 = *(const f32x4*)(y + (size_t)s1 * H_DIM + c);
  f32x4 v2 = *(const f32x4*)(y + (size_t)s2 * H_DIM + c);
  f32x4 v3 = *(const f32x4*)(y + (size_t)s3 * H_DIM + c);
  f32x4 r = (v0 + v1) + (v2 + v3);
  *(f32x4*)(out + (size_t)t * H_DIM + c) = r;
}

// ---------------- launch ----------------
extern "C" void kernel_launch(void* const* d_in, const int* in_sizes, int n_in,
                              void* d_out, int out_size, void* d_ws, size_t ws_size,
                              hipStream_t stream) {
  const float* hs       = (const float*)d_in[0];
  const int*   topk_idx = (const int*)d_in[1];
  const float* topk_w   = (const float*)d_in[2];
  const float* w_gu     = (const float*)d_in[3];   // [16][1536][1024]
  const float* w_d      = (const float*)d_in[4];   // [16][1024][768]
  float* out = (float*)d_out;

  char* ws = (char*)d_ws;
  unsigned short* Xbf  = (unsigned short*)(ws);                 //  4,194,304
  unsigned short* WguK = (unsigned short*)(ws + 4194304);       // 50,331,648
  float*          y    = (float*)(ws + 4194304);                // alias WguK (dead after gemm1)
  unsigned short* hbuf = (unsigned short*)(ws + 54525952);      // 18,874,368
  int*   slot_tok       = (int*)(ws + 73400320);                //     49,152
  float* slot_w         = (float*)(ws + 73449472);              //     49,152
  int*   slot_of        = (int*)(ws + 73498624);                //     32,768
  int*   tile_expert    = (int*)(ws + 73531392);                //        256
  int*   tile_expert128 = (int*)(ws + 73531648);                //        384
  // total ~73.5 MB

  cvt_bf16_kernel<<<1024, 256, 0, stream>>>(hs, Xbf, T_TOK * H_DIM / 8);
  route_kernel<<<1, 256, 0, stream>>>(topk_idx, topk_w, slot_tok, slot_w,
                                      slot_of, tile_expert, tile_expert128);
  wtrans_kernel<<<RTOT_GU / 16, 256, 0, stream>>>(w_gu, WguK, H_DIM, RTOT_GU);

  gemm1_kernel<<<dim3(6, NT256), 512, 0, stream>>>(Xbf, WguK, slot_tok, tile_expert, hbuf);
  gemm2_kernel<<<dim3(8, NT128), 256, 0, stream>>>(hbuf, w_d, slot_tok, slot_w, tile_expert128, y);
  combine_kernel<<<T_TOK, 256, 0, stream>>>(y, slot_of, out);
}